// Round 11
// baseline (384.435 us; speedup 1.0000x reference)
//
#include <hip/hip_runtime.h>
#include <math.h>

// Planar normalizing flow, B=524288 rows, D=64, F=32.
// r6's 3-phase small-state structure (c = x.W^T -> triangular h recurrence
// -> z = x + Uhat^T h; 32-float carried state -> honest VGPR allocation),
// with ONE change: param matrices (wt, Gt, uhat) are read via
// UNIFORM-ADDRESS VECTOR loads instead of s_loads. A wave-uniform
// global_load_dwordx4 is a single broadcast L1 access (param set 20.6KB <
// 32KB L1), but lands in VGPRs: vmcnt-tracked, deeply pipelinable -- unlike
// s_loads, where the ~112-SGPR file holds only 2-3 batches in flight (the
// measured stall in r6: VALUBusy 30%, 135us). The opaque-zero `vz` (inline
// asm v_mov) defeats uniformity analysis so the compiler emits VMEM loads.
// Params-via-LDS (r8) and per-lane-divergent VMEM (r5) are measured dead
// ends; z-carry 64-float state is always AGPR-parked (r1/r4/r9).

#define NF_D 64
#define NF_F 32

typedef float f4 __attribute__((ext_vector_type(4)));

// wsbuf layout (floats): wt[64][32] | Gt[32][32] | uhat[32][64] | wuh[32]
#define W_WT   0
#define W_GT   2048
#define W_UH   3072
#define W_WUH  5120
#define W_TOT  5152

// --- precompute: u_hat, wuh, W^T, G -------------------------------------
__global__ void nf_precompute(const float* __restrict__ us,
                              const float* __restrict__ ws,
                              float* __restrict__ wsbuf) {
  __shared__ float s_u[NF_F][NF_D];
  int t = threadIdx.x;
  if (t < NF_F) {
    const float* u = us + t * NF_D;
    const float* w = ws + t * NF_D;
    float wu = 0.f, n2 = 0.f;
    for (int d = 0; d < NF_D; ++d) {
      wu = fmaf(u[d], w[d], wu);
      n2 = fmaf(w[d], w[d], n2);
    }
    float sp = fmaxf(wu, 0.f) + log1pf(expf(-fabsf(wu)));  // softplus
    float coef = (sp - 1.f - wu) / sqrtf(n2);
    for (int d = 0; d < NF_D; ++d) {
      float uh = fmaf(coef, w[d], u[d]);
      s_u[t][d] = uh;
      wsbuf[W_UH + t * NF_D + d] = uh;
    }
    wsbuf[W_WUH + t] = fmaf(coef, n2, wu);       // w_t . u_hat_t
  }
  __syncthreads();
  for (int i = t; i < NF_D * NF_F; i += 256) {   // wt[d][f] = ws[f][d]
    int d = i / NF_F, f = i % NF_F;
    wsbuf[W_WT + i] = ws[f * NF_D + d];
  }
  for (int i = t; i < NF_F * NF_F; i += 256) {   // Gt[f][g] = u_hat_g . w_f
    int f = i / NF_F, g = i % NF_F;
    float s = 0.f;
    if (g < f) {
      const float* w = ws + f * NF_D;
      for (int d = 0; d < NF_D; ++d) s = fmaf(s_u[g][d], w[d], s);
    }
    wsbuf[W_GT + i] = s;                         // zero-padded for g >= f
  }
}

// tanh(x) = 1 - 2/(e^{2x}+1); hardware exp2/rcp; saturates to +-1.
__device__ __forceinline__ float fast_tanh(float x) {
  float e = __builtin_amdgcn_exp2f(x * 2.885390081777927f); // 2*log2(e)
  return 1.f - 2.f * __builtin_amdgcn_rcpf(e + 1.f);
}

// --- main: one thread per row, params via uniform-address VMEM loads -----
__global__ __launch_bounds__(256) void nf_main(
    const float* __restrict__ x,
    const float* __restrict__ bs,
    const float* __restrict__ wsbuf,
    float* __restrict__ out_z,
    float* __restrict__ out_ld,
    int B) {
  // Opaque zero: a VGPR the compiler cannot prove uniform/constant.
  // Param addresses gain a vector component -> global_load_dwordx4
  // (single broadcast L1 access/wave) instead of s_load.
  int vz;
  asm volatile("v_mov_b32 %0, 0" : "=v"(vz));

  const float* __restrict__ wt = wsbuf + W_WT + vz;  // VMEM path
  const float* __restrict__ Gt = wsbuf + W_GT + vz;  // VMEM path
  const float* __restrict__ uh = wsbuf + W_UH + vz;  // VMEM path
  const float* __restrict__ wuh = wsbuf + W_WUH;     // scalar (tiny)

  int row = blockIdx.x * blockDim.x + threadIdx.x;
  if (row >= B) return;
  const f4* __restrict__ xv = reinterpret_cast<const f4*>(x + (size_t)row * NF_D);

  // ---- Phase A: c[f] = x . w_f via transposed wt ------------------------
  f4 c[NF_F / 4];
  #pragma unroll
  for (int q = 0; q < NF_F / 4; ++q) c[q] = (f4)(0.f);
  #pragma unroll 2
  for (int dc = 0; dc < NF_D / 4; ++dc) {
    f4 xd = xv[dc];
    #pragma unroll
    for (int j = 0; j < 4; ++j) {
      const f4* __restrict__ wr =
          reinterpret_cast<const f4*>(wt + (dc * 4 + j) * NF_F);
      #pragma unroll
      for (int q = 0; q < NF_F / 4; ++q)
        c[q] += wr[q] * xd[j];               // v_pk_fma_f32
    }
  }

  // ---- Phase B: triangular recurrence, h overwrites c -------------------
  float ldp = 1.f;
  #pragma unroll
  for (int f = 0; f < NF_F; ++f) {
    const f4* __restrict__ g4 = reinterpret_cast<const f4*>(Gt + f * NF_F);
    f4 a = (f4)(0.f);
    #pragma unroll
    for (int q = 0; q < (f + 3) / 4; ++q)    // zero-padded triangular
      a += g4[q] * c[q];
    float s = c[f / 4][f % 4] + bs[f] + ((a.x + a.y) + (a.z + a.w));
    float hf = fast_tanh(s);
    ldp *= fmaf(fmaf(-hf, hf, 1.f), wuh[f], 1.f);
    c[f / 4][f % 4] = hf;                    // h replaces c
  }

  // ---- Phase C: z = x + Uhat^T h ----------------------------------------
  f4* __restrict__ ov = reinterpret_cast<f4*>(out_z + (size_t)row * NF_D);
  #pragma unroll 2
  for (int dc = 0; dc < NF_D / 4; ++dc) {
    f4 acc = xv[dc];                          // x re-read: L3-resident
    #pragma unroll
    for (int f = 0; f < NF_F; ++f)
      acc += *reinterpret_cast<const f4*>(uh + f * NF_D + dc * 4)
             * c[f / 4][f % 4];
    ov[dc] = acc;
  }
  out_ld[row] = __builtin_amdgcn_logf(fabsf(ldp)) * 0.6931471805599453f;
}

extern "C" void kernel_launch(void* const* d_in, const int* in_sizes, int n_in,
                              void* d_out, int out_size, void* d_ws, size_t ws_size,
                              hipStream_t stream) {
  const float* x    = (const float*)d_in[0];
  const float* us   = (const float*)d_in[1];
  const float* ws_p = (const float*)d_in[2];
  const float* bs   = (const float*)d_in[3];
  const int B = in_sizes[0] / NF_D;

  float* wsbuf = (float*)d_ws;   // W_TOT floats ~ 20.6 KB
  float* out   = (float*)d_out;  // z [B*64] then sum_log_det [B]

  nf_precompute<<<1, 256, 0, stream>>>(us, ws_p, wsbuf);
  const int block = 256;
  const int grid = (B + block - 1) / block;
  nf_main<<<grid, block, 0, stream>>>(x, bs, wsbuf,
                                      out, out + (size_t)B * NF_D, B);
}

// Round 12
// 82.663 us; speedup vs baseline: 4.6506x; 4.6506x over previous
//
#include <hip/hip_runtime.h>
#include <math.h>

// Planar normalizing flow, B=524288 rows, D=64, F=32 -- MFMA formulation.
//   Phase A (MFMA): S[32f x 64b] = W . X_tile^T   (per 64-row tile)
//   Phase B (VALU): per-lane row recurrence h[f] = tanh(S + b + G.h), logdet
//   Phase C (MFMA): Z = X + Uhat^T h
// Params W/Uhat live in per-lane MFMA fragments loaded ONCE (48 VGPR) --
// eliminates the param-delivery problem that killed r5/r6/r8/r11 (s_load
// SGPR ceiling, LDS-pipe, L1-port, uniform-VMEM spill). G (4KB) stays on
// s_load but amortized over 64 rows/wave (300x less than r6). Carried
// vector state is h[32] -- the honest-allocation regime (r5/r6/r10).
// Layout-risk containment: fragment k-order (k = 8*(lane>>4)+j) is applied
// identically to BOTH operands of every MFMA, so results are invariant to
// the true hardware k-permutation; only C/D (HW-verified: col=lane&15,
// row=4*(lane>>4)+reg) and A-row/B-col = lane&15 are assumed.
// Precision: phase A uses bf16 hi/lo split (trunc) of both X and W, 3
// passes (hi*hi + hi*lo + lo*hi): rel err ~2^-16. Phase C single bf16
// (h,u ~ 0.07-1: abs err ~1e-3). G-dot in fp32.

#define NF_D 64
#define NF_F 32

typedef float f4 __attribute__((ext_vector_type(4)));
typedef float f32x4v __attribute__((ext_vector_type(4)));
typedef unsigned int u32;
typedef u32 u32x4 __attribute__((ext_vector_type(4)));
typedef short bf16x8 __attribute__((ext_vector_type(8)));

// wsbuf layout in 4-byte units:
#define WS_WF   0       // u32[8][64][4]  W A-frags, lin=(Mt*2+Kt)*2+p
#define WS_UF   2048    // u32[4][64][4]  Uhat B-frags (Nt)
#define WS_GT   3072    // float[32][32]  G[f][g]=w_f.uhat_g (g<f else 0)
#define WS_WUH  4096    // float[32]      w_f.uhat_f
#define WS_TOT  4128

__device__ __forceinline__ u32 fbits(float x){ union{float f;u32 u;} c; c.f=x; return c.u; }
__device__ __forceinline__ float asf(u32 u){ union{u32 u;float f;} c; c.u=u; return c.f; }
__device__ __forceinline__ u32 bfrnd(float x){ u32 b=fbits(x); return (b + 0x7FFFu + ((b>>16)&1u)) >> 16; }
__device__ __forceinline__ bf16x8 asbf(u32x4 v){ union{u32x4 u; bf16x8 b;} c; c.u=v; return c.b; }

// --- precompute: uhat, wuh, G, and the W/U fragment buffers --------------
__global__ void nf_precompute(const float* __restrict__ us,
                              const float* __restrict__ ws,
                              u32* __restrict__ wsb) {
  __shared__ float s_u[NF_F][NF_D];
  float* wsf = (float*)wsb;
  int t = threadIdx.x;
  if (t < NF_F) {
    const float* u = us + t * NF_D;
    const float* w = ws + t * NF_D;
    float wu = 0.f, n2 = 0.f;
    for (int d = 0; d < NF_D; ++d) {
      wu = fmaf(u[d], w[d], wu);
      n2 = fmaf(w[d], w[d], n2);
    }
    float sp = fmaxf(wu, 0.f) + log1pf(expf(-fabsf(wu)));  // softplus
    float coef = (sp - 1.f - wu) / sqrtf(n2);
    for (int d = 0; d < NF_D; ++d)
      s_u[t][d] = fmaf(coef, w[d], u[d]);                  // uhat
    wsf[WS_WUH + t] = fmaf(coef, n2, wu);                  // w_t.uhat_t
  }
  __syncthreads();
  // W A-frags: lane l holds W[fm=16Mt+(l&15)][k=32Kt+8*(l>>4)+j], j=0..7
  // p=0: bf16-trunc(hi); p=1: bf16-trunc(w - hi)
  for (int idx = t; idx < 8 * 64; idx += 256) {
    int lin = idx >> 6, l = idx & 63;
    int Mt = lin >> 2, Kt = (lin >> 1) & 1, p = lin & 1;
    int fm = 16 * Mt + (l & 15);
    int kb = 32 * Kt + 8 * (l >> 4);
    for (int i = 0; i < 4; ++i) {
      u32 pr[2];
      for (int e = 0; e < 2; ++e) {
        float w = ws[fm * NF_D + kb + 2 * i + e];
        u32 hb = fbits(w) & 0xFFFF0000u;
        pr[e] = (p == 0) ? (hb >> 16) : (fbits(w - asf(hb)) >> 16);
      }
      wsb[WS_WF + (lin * 64 + l) * 4 + i] = pr[0] | (pr[1] << 16);
    }
  }
  // U B-frags: lane l holds Uhat[f=8*(l>>4)+j][d=16Nt+(l&15)], rounded bf16
  for (int idx = t; idx < 4 * 64; idx += 256) {
    int l = idx & 63;
    int d = 16 * (idx >> 6) + (l & 15);
    int fb = 8 * (l >> 4);
    for (int i = 0; i < 4; ++i) {
      u32 r0 = bfrnd(s_u[fb + 2 * i][d]);
      u32 r1 = bfrnd(s_u[fb + 2 * i + 1][d]);
      wsb[WS_UF + idx * 4 + i] = r0 | (r1 << 16);
    }
  }
  // G[f][g] = w_f . uhat_g for g<f, else 0
  for (int i = t; i < NF_F * NF_F; i += 256) {
    int f = i >> 5, g = i & 31;
    float s = 0.f;
    if (g < f) {
      const float* w = ws + f * NF_D;
      for (int d = 0; d < NF_D; ++d) s = fmaf(s_u[g][d], w[d], s);
    }
    wsf[WS_GT + i] = s;
  }
}

// tanh(x) = 1 - 2/(e^{2x}+1); hardware exp2/rcp; saturates to +-1.
__device__ __forceinline__ float fast_tanh(float x) {
  float e = __builtin_amdgcn_exp2f(x * 2.885390081777927f); // 2*log2(e)
  return 1.f - 2.f * __builtin_amdgcn_rcpf(e + 1.f);
}

#define MFMA __builtin_amdgcn_mfma_f32_16x16x32_bf16

// --- main: one 64-row tile per wave --------------------------------------
__global__ __launch_bounds__(256) void nf_main(
    const float* __restrict__ x,
    const float* __restrict__ bs,
    const u32* __restrict__ wsb,
    float* __restrict__ out_z,
    float* __restrict__ out_ld,
    int B) {
  __shared__ float S[4][64 * 33];   // per-wave S[b][f], stride 33
  __shared__ u32 H2[4][16 * 64];    // per-wave packed h pairs [f/2][b]
  const float* wsf = (const float*)wsb;

  int wave = threadIdx.x >> 6;
  int l = threadIdx.x & 63;
  int ntiles = B / 64;
  int tile = blockIdx.x * 4 + wave;
  if (tile >= ntiles) tile = ntiles - 1;   // clamp (no early exit: barriers)
  float* Sw = S[wave];
  u32* Hw = H2[wave];

  // persistent param fragments (once per wave)
  bf16x8 Wf[2][2][2], Uf[4];
  #pragma unroll
  for (int q = 0; q < 8; ++q)
    Wf[q >> 2][(q >> 1) & 1][q & 1] =
        asbf(*(const u32x4*)(wsb + WS_WF + (q * 64 + l) * 4));
  #pragma unroll
  for (int Nt = 0; Nt < 4; ++Nt)
    Uf[Nt] = asbf(*(const u32x4*)(wsb + WS_UF + (Nt * 64 + l) * 4));

  const float* xt = x + (size_t)tile * 64 * NF_D;

  // ---- Phase A: S = W . X^T (split bf16, 3 passes) ----------------------
  f32x4v acc[2][4];
  #pragma unroll
  for (int Nt = 0; Nt < 4; ++Nt) {
    bf16x8 Xh[2], Xl[2];
    #pragma unroll
    for (int Kt = 0; Kt < 2; ++Kt) {
      const f4* xp = (const f4*)(xt + ((l & 15) + 16 * Nt) * NF_D +
                                 32 * Kt + 8 * (l >> 4));
      f4 xa = xp[0], xb = xp[1];
      float xs[8] = {xa.x, xa.y, xa.z, xa.w, xb.x, xb.y, xb.z, xb.w};
      u32x4 hw, lw;
      #pragma unroll
      for (int i = 0; i < 4; ++i) {
        u32 b0 = fbits(xs[2 * i]), b1 = fbits(xs[2 * i + 1]);
        u32 h0 = b0 & 0xFFFF0000u, h1 = b1 & 0xFFFF0000u;
        hw[i] = (h0 >> 16) | h1;
        lw[i] = (fbits(xs[2 * i] - asf(h0)) >> 16) |
                (fbits(xs[2 * i + 1] - asf(h1)) & 0xFFFF0000u);
      }
      Xh[Kt] = asbf(hw);
      Xl[Kt] = asbf(lw);
    }
    #pragma unroll
    for (int Mt = 0; Mt < 2; ++Mt) {
      f32x4v a = {0.f, 0.f, 0.f, 0.f};
      #pragma unroll
      for (int Kt = 0; Kt < 2; ++Kt) {
        a = MFMA(Wf[Mt][Kt][0], Xh[Kt], a, 0, 0, 0);
        a = MFMA(Wf[Mt][Kt][0], Xl[Kt], a, 0, 0, 0);
        a = MFMA(Wf[Mt][Kt][1], Xh[Kt], a, 0, 0, 0);
      }
      acc[Mt][Nt] = a;
    }
  }
  // scatter S to LDS: C/D layout col=lane&15 (b-in-Ntile), row=4*(l>>4)+r
  #pragma unroll
  for (int Mt = 0; Mt < 2; ++Mt)
    #pragma unroll
    for (int Nt = 0; Nt < 4; ++Nt)
      #pragma unroll
      for (int r = 0; r < 4; ++r)
        Sw[((l & 15) + 16 * Nt) * 33 + 16 * Mt + 4 * (l >> 4) + r] =
            acc[Mt][Nt][r];
  __syncthreads();   // forces lgkmcnt before cross-lane reads (no early exit)

  // ---- Phase B: per-lane row recurrence (lane = row b) ------------------
  const float* gt = wsf + WS_GT;
  const float* wuhp = wsf + WS_WUH;
  float h[NF_F];
  float ldp = 1.f;
  #pragma unroll
  for (int f = 0; f < NF_F; ++f) {
    float s = Sw[l * 33 + f] + bs[f];
    #pragma unroll
    for (int g = 0; g < f; ++g)
      s = fmaf(gt[f * 32 + g], h[g], s);     // G: wave-uniform s_loads
    float hf = fast_tanh(s);
    h[f] = hf;
    ldp *= fmaf(fmaf(-hf, hf, 1.f), wuhp[f], 1.f);
  }
  // pack h -> bf16 pairs in LDS: Hw[f2][b], b = lane
  #pragma unroll
  for (int i = 0; i < 16; ++i)
    Hw[i * 64 + l] = (fbits(h[2 * i]) >> 16) | (fbits(h[2 * i + 1]) & 0xFFFF0000u);
  __syncthreads();

  // ---- Phase C: Z = X + Uhat^T h ----------------------------------------
  float* zt = out_z + (size_t)tile * 64 * NF_D;
  #pragma unroll
  for (int Mt = 0; Mt < 4; ++Mt) {
    u32x4 hfw;
    #pragma unroll
    for (int i = 0; i < 4; ++i)
      hfw[i] = Hw[(4 * (l >> 4) + i) * 64 + (l & 15) + 16 * Mt];
    bf16x8 Hf = asbf(hfw);
    #pragma unroll
    for (int Nt = 0; Nt < 4; ++Nt) {
      f32x4v zz = {0.f, 0.f, 0.f, 0.f};
      zz = MFMA(Hf, Uf[Nt], zz, 0, 0, 0);
      #pragma unroll
      for (int r = 0; r < 4; ++r) {
        int brow = 16 * Mt + 4 * (l >> 4) + r;
        int d = (l & 15) + 16 * Nt;
        zt[brow * NF_D + d] = zz[r] + xt[brow * NF_D + d];
      }
    }
  }
  out_ld[(size_t)tile * 64 + l] =
      __builtin_amdgcn_logf(fabsf(ldp)) * 0.6931471805599453f;
}

extern "C" void kernel_launch(void* const* d_in, const int* in_sizes, int n_in,
                              void* d_out, int out_size, void* d_ws, size_t ws_size,
                              hipStream_t stream) {
  const float* x    = (const float*)d_in[0];
  const float* us   = (const float*)d_in[1];
  const float* ws_p = (const float*)d_in[2];
  const float* bs   = (const float*)d_in[3];
  const int B = in_sizes[0] / NF_D;

  u32* wsbuf = (u32*)d_ws;       // WS_TOT u32 ~ 16.5 KB
  float* out = (float*)d_out;    // z [B*64] then sum_log_det [B]

  nf_precompute<<<1, 256, 0, stream>>>(us, ws_p, wsbuf);
  const int ntiles = B / 64;
  const int grid = (ntiles + 3) / 4;
  nf_main<<<grid, 256, 0, stream>>>(x, bs, wsbuf, out,
                                    out + (size_t)B * NF_D, B);
}